// Round 4
// baseline (132.719 us; speedup 1.0000x reference)
//
#include <hip/hip_runtime.h>
#include <math.h>

#define NOBS 9
#define LATD 128

typedef unsigned u32x2 __attribute__((ext_vector_type(2)));

__device__ __forceinline__ float silu_f(float x) { return x / (1.f + expf(-x)); }

// ---------------- lane-exchange primitives ----------------

template<int CTRL>
__device__ __forceinline__ float dpp_perm(float x) {
  return __int_as_float(__builtin_amdgcn_update_dpp(0, __float_as_int(x), CTRL, 0xF, 0xF, true));
}
template<int PAT>
__device__ __forceinline__ float ds_swz(float x) {
  return __int_as_float(__builtin_amdgcn_ds_swizzle(__float_as_int(x), PAT));
}

// xor4: ds_swizzle xor-mask 4 (only remaining DS-pipe exchange)
__device__ __forceinline__ float x4(float x) { return ds_swz<0x101F>(x); }

#if __has_builtin(__builtin_amdgcn_permlane32_swap)
#define PL32 1
__device__ __forceinline__ float x32(float x, bool sel) {
  u32x2 r = __builtin_amdgcn_permlane32_swap(__float_as_uint(x), __float_as_uint(x), false, false);
  return __uint_as_float(sel ? r.x : r.y);
}
__device__ __forceinline__ float sum32(float x) {
  u32x2 r = __builtin_amdgcn_permlane32_swap(__float_as_uint(x), __float_as_uint(x), false, false);
  return __uint_as_float(r.x) + __uint_as_float(r.y);
}
#else
#define PL32 0
__device__ __forceinline__ float x32(float x, bool sel) { return __shfl_xor(x, 32, 64); }
__device__ __forceinline__ float sum32(float x) { return x + __shfl_xor(x, 32, 64); }
#endif

#if __has_builtin(__builtin_amdgcn_permlane16_swap)
#define PL16 1
__device__ __forceinline__ float x16(float x, bool sel) {
  u32x2 r = __builtin_amdgcn_permlane16_swap(__float_as_uint(x), __float_as_uint(x), false, false);
  return __uint_as_float(sel ? r.x : r.y);
}
__device__ __forceinline__ float sum16(float x) {
  u32x2 r = __builtin_amdgcn_permlane16_swap(__float_as_uint(x), __float_as_uint(x), false, false);
  return __uint_as_float(r.x) + __uint_as_float(r.y);
}
#else
#define PL16 0
__device__ __forceinline__ float x16(float x, bool sel) { return ds_swz<0x401F>(x); }
__device__ __forceinline__ float sum16(float x) { return x + ds_swz<0x401F>(x); }
#endif

__device__ __forceinline__ float wave_sum(float x) {
  x += dpp_perm<0xB1>(x);    // xor1
  x += dpp_perm<0x4E>(x);    // xor2
  x += x4(x);                // xor4
  x += dpp_perm<0x128>(x);   // xor8
  x = sum16(x);
  x = sum32(x);
  return x;
}

// ---------------- circuit gates ----------------
// amp index bits: [9:6] = reg bits 3..0 (qubits 0..3), [5:0] = lane bits (qubits 4..9)

template<int M>
__device__ __forceinline__ void ry_reg(float v[16], float c, float s) {
#pragma unroll
  for (int r = 0; r < 16; ++r) {
    if ((r & M) == 0) {
      float p0 = v[r], p1 = v[r | M];
      v[r]     = c * p0 - s * p1;
      v[r | M] = s * p0 + c * p1;
    }
  }
}

__device__ __forceinline__ void apply_rys(float v[16], int lane, bool sel32, bool sel16,
                                          const float* __restrict__ cc,
                                          const float* __restrict__ ss) {
  ry_reg<8>(v, cc[0], ss[0]);
  ry_reg<4>(v, cc[1], ss[1]);
  ry_reg<2>(v, cc[2], ss[2]);
  ry_reg<1>(v, cc[3], ss[3]);
  { float c = cc[4], s = ss[4], sp = (lane & 32) ? s : -s;   // q4: xor32
#pragma unroll
    for (int r = 0; r < 16; ++r) { float p = x32(v[r], sel32); v[r] = fmaf(c, v[r], sp * p); } }
  { float c = cc[5], s = ss[5], sp = (lane & 16) ? s : -s;   // q5: xor16
#pragma unroll
    for (int r = 0; r < 16; ++r) { float p = x16(v[r], sel16); v[r] = fmaf(c, v[r], sp * p); } }
  { float c = cc[6], s = ss[6], sp = (lane & 8) ? s : -s;    // q6: xor8 (DPP ror8)
#pragma unroll
    for (int r = 0; r < 16; ++r) { float p = dpp_perm<0x128>(v[r]); v[r] = fmaf(c, v[r], sp * p); } }
  { float c = cc[7], s = ss[7], sp = (lane & 4) ? s : -s;    // q7: xor4 (swizzle)
#pragma unroll
    for (int r = 0; r < 16; ++r) { float p = x4(v[r]); v[r] = fmaf(c, v[r], sp * p); } }
  { float c = cc[8], s = ss[8], sp = (lane & 2) ? s : -s;    // q8: xor2
#pragma unroll
    for (int r = 0; r < 16; ++r) { float p = dpp_perm<0x4E>(v[r]); v[r] = fmaf(c, v[r], sp * p); } }
  { float c = cc[9], s = ss[9], sp = (lane & 1) ? s : -s;    // q9: xor1
#pragma unroll
    for (int r = 0; r < 16; ++r) { float p = dpp_perm<0xB1>(v[r]); v[r] = fmaf(c, v[r], sp * p); } }
}

__device__ __forceinline__ void cnot_ladder(float v[16], int lane, bool sel32, bool sel16) {
  float t;
  // even phase: (0,1),(2,3) reg-reg; (4,5),(6,7),(8,9) lane-lane
  t=v[8];  v[8]=v[12];  v[12]=t;   // ctrl q0 (bit3) -> tgt q1 (bit2)
  t=v[9];  v[9]=v[13];  v[13]=t;
  t=v[10]; v[10]=v[14]; v[14]=t;
  t=v[11]; v[11]=v[15]; v[15]=t;
  t=v[2];  v[2]=v[3];   v[3]=t;    // ctrl q2 (bit1) -> tgt q3 (bit0)
  t=v[6];  v[6]=v[7];   v[7]=t;
  t=v[10]; v[10]=v[11]; v[11]=t;
  t=v[14]; v[14]=v[15]; v[15]=t;
  { bool c45 = (lane & 32);        // ctrl q4 -> tgt q5 (xor16)
#pragma unroll
    for (int r = 0; r < 16; ++r) { float p = x16(v[r], sel16); v[r] = c45 ? p : v[r]; } }
  { bool c67 = (lane & 8);         // ctrl q6 -> tgt q7 (xor4)
#pragma unroll
    for (int r = 0; r < 16; ++r) { float p = x4(v[r]); v[r] = c67 ? p : v[r]; } }
  { bool c89 = (lane & 2);         // ctrl q8 -> tgt q9 (xor1)
#pragma unroll
    for (int r = 0; r < 16; ++r) { float p = dpp_perm<0xB1>(v[r]); v[r] = c89 ? p : v[r]; } }
  // odd phase: (1,2) reg-reg; (3,4) reg-lane; (5,6),(7,8) lane-lane
  t=v[4];  v[4]=v[6];   v[6]=t;    // ctrl q1 (bit2) -> tgt q2 (bit1)
  t=v[5];  v[5]=v[7];   v[7]=t;
  t=v[12]; v[12]=v[14]; v[14]=t;
  t=v[13]; v[13]=v[15]; v[15]=t;
#pragma unroll
  for (int r = 1; r < 16; r += 2) v[r] = x32(v[r], sel32);  // ctrl q3 (reg bit0) -> tgt q4 (xor32)
  { bool c56 = (lane & 16);        // ctrl q5 -> tgt q6 (xor8)
#pragma unroll
    for (int r = 0; r < 16; ++r) { float p = dpp_perm<0x128>(v[r]); v[r] = c56 ? p : v[r]; } }
  { bool c78 = (lane & 4);         // ctrl q7 -> tgt q8 (xor2)
#pragma unroll
    for (int r = 0; r < 16; ++r) { float p = dpp_perm<0x4E>(v[r]); v[r] = c78 ? p : v[r]; } }
}

// ---------------- fused kernel: 2 batch rows per 128-thread block ----------------

__global__ __launch_bounds__(128) void fused_kernel(
    const float* __restrict__ z, const float* __restrict__ t,
    const float* __restrict__ W1, const float* __restrict__ b1,
    const float* __restrict__ W2, const float* __restrict__ b2,
    const float* __restrict__ varp,
    const float* __restrict__ A_p, const float* __restrict__ D_p,
    const float* __restrict__ W3, const float* __restrict__ b3,
    const float* __restrict__ W4, const float* __restrict__ b4,
    float* __restrict__ out) {
  __shared__ float xs[2][256];
  __shared__ float hs[2][256];
  __shared__ float dump[2][1024];
  __shared__ float cs[2][40], sn[2][40];
  __shared__ float vcs[60], vsn[60];
  __shared__ float os[2][NOBS];

  int tid = threadIdx.x;          // 0..127
  int b0 = blockIdx.x * 2;

  // var-layer cos/sin (redundant per block, trivial)
  if (tid < 60) {
    float s, c;
    sincosf(0.5f * varp[tid], &s, &c);
    vcs[tid] = c; vsn[tid] = s;
  }

  // ---- phase 1: x = [z, cos(t f), sin(t f)] ----
  {
    int j = tid & 63;
    float freq = expf(-9.2103403719761836f * (float)j * (1.f / 64.f));
#pragma unroll
    for (int r = 0; r < 2; ++r) {
      int b = b0 + r;
      xs[r][tid] = z[b * 128 + tid];
      float arg = t[b] * freq;
      xs[r][tid + 128] = (tid < 64) ? cosf(arg) : sinf(arg);
    }
  }
  __syncthreads();

  // ---- phase 2: h = silu(x@W1 + b1)  (2 rows, each thread 2 cols) ----
  {
    float a00 = b1[tid],       a10 = a00;
    float a01 = b1[tid + 128], a11 = a01;
#pragma unroll 4
    for (int k = 0; k < 256; k += 4) {
      float w00 = W1[(k + 0) * 256 + tid], w01 = W1[(k + 0) * 256 + tid + 128];
      float w10 = W1[(k + 1) * 256 + tid], w11 = W1[(k + 1) * 256 + tid + 128];
      float w20 = W1[(k + 2) * 256 + tid], w21 = W1[(k + 2) * 256 + tid + 128];
      float w30 = W1[(k + 3) * 256 + tid], w31 = W1[(k + 3) * 256 + tid + 128];
      float4 x0 = *(const float4*)&xs[0][k];
      float4 x1 = *(const float4*)&xs[1][k];
      a00 = fmaf(x0.w, w30, fmaf(x0.z, w20, fmaf(x0.y, w10, fmaf(x0.x, w00, a00))));
      a01 = fmaf(x0.w, w31, fmaf(x0.z, w21, fmaf(x0.y, w11, fmaf(x0.x, w01, a01))));
      a10 = fmaf(x1.w, w30, fmaf(x1.z, w20, fmaf(x1.y, w10, fmaf(x1.x, w00, a10))));
      a11 = fmaf(x1.w, w31, fmaf(x1.z, w21, fmaf(x1.y, w11, fmaf(x1.x, w01, a11))));
    }
    hs[0][tid]       = silu_f(a00);
    hs[0][tid + 128] = silu_f(a01);
    hs[1][tid]       = silu_f(a10);
    hs[1][tid + 128] = silu_f(a11);
  }
  __syncthreads();

  // ---- phase 3: ang = h@W2 + b2 -> cos/sin(ang/2)  (80 outputs) ----
  if (tid < 80) {
    int r = tid / 40, c = tid - r * 40;
    float acc = b2[c];
#pragma unroll 4
    for (int k = 0; k < 256; k += 4) {
      float4 h = *(const float4*)&hs[r][k];
      acc = fmaf(h.x, W2[(k + 0) * 40 + c], acc);
      acc = fmaf(h.y, W2[(k + 1) * 40 + c], acc);
      acc = fmaf(h.z, W2[(k + 2) * 40 + c], acc);
      acc = fmaf(h.w, W2[(k + 3) * 40 + c], acc);
    }
    float s, cv;
    sincosf(0.5f * acc, &s, &cv);
    cs[r][c] = cv; sn[r][c] = s;
  }
  __syncthreads();

  // ---- phase 4: quantum circuit, wave w = batch row b0+w ----
  {
    int wave = tid >> 6;
    int lane = tid & 63;
    // runtime polarity probe for permlane swaps
    bool sel32 = true, sel16 = true;
#if PL32
    { u32x2 tt = __builtin_amdgcn_permlane32_swap((unsigned)lane, (unsigned)lane, false, false);
      sel32 = (tt.x == (unsigned)(lane ^ 32)); }
#endif
#if PL16
    { u32x2 tt = __builtin_amdgcn_permlane16_swap((unsigned)lane, (unsigned)lane, false, false);
      sel16 = (tt.x == (unsigned)(lane ^ 16)); }
#endif
    const float* cc = cs[wave];
    const float* ss = sn[wave];

    // layer 0 on |0...0>: product state
    float base = 1.f;
    base *= (lane & 32) ? ss[4] : cc[4];
    base *= (lane & 16) ? ss[5] : cc[5];
    base *= (lane & 8)  ? ss[6] : cc[6];
    base *= (lane & 4)  ? ss[7] : cc[7];
    base *= (lane & 2)  ? ss[8] : cc[8];
    base *= (lane & 1)  ? ss[9] : cc[9];
    float v[16];
#pragma unroll
    for (int r = 0; r < 16; ++r) {
      float p = base;
      p *= (r & 8) ? ss[0] : cc[0];
      p *= (r & 4) ? ss[1] : cc[1];
      p *= (r & 2) ? ss[2] : cc[2];
      p *= (r & 1) ? ss[3] : cc[3];
      v[r] = p;
    }
    cnot_ladder(v, lane, sel32, sel16);
#pragma unroll 1
    for (int layer = 1; layer < 4; ++layer) {
      apply_rys(v, lane, sel32, sel16, cc + layer * 10, ss + layer * 10);
      if (layer < 3) cnot_ladder(v, lane, sel32, sel16);
    }
#pragma unroll 1
    for (int ly = 0; ly < 6; ++ly) {
      apply_rys(v, lane, sel32, sel16, vcs + ly * 10, vsn + ly * 10);
      cnot_ladder(v, lane, sel32, sel16);
    }

    float* sw = dump[wave];
#pragma unroll
    for (int r = 0; r < 16; ++r) sw[r * 64 + lane] = v[r];

    // expectation values (obs s acts on amp bits (9-s, 8-s))
#pragma unroll 1
    for (int s = 0; s < NOBS; ++s) {
      const int r8 = 8 - s;
      const int stride = 1 << r8;
      float h10 = A_p[s*6+0], h20 = A_p[s*6+1], h21 = A_p[s*6+2];
      float h30 = A_p[s*6+3], h31 = A_p[s*6+4], h32 = A_p[s*6+5];
      float d0 = 2.f * D_p[s*4+1], d1 = 2.f * D_p[s*4+2], d2 = 2.f * D_p[s*4+3];
      float acc = 0.f;
#pragma unroll
      for (int k = 0; k < 4; ++k) {
        int p = lane + 64 * k;
        int a  = p >> r8;
        int rr = p & (stride - 1);
        int bse = (a << (r8 + 2)) + rr;
        float x0 = sw[bse];
        float x1 = sw[bse + stride];
        float x2 = sw[bse + 2 * stride];
        float x3 = sw[bse + 3 * stride];
        acc += d0 * x0 * x0 + d1 * x1 * x1 + d2 * x2 * x2
             + 2.f * (h10 * x1 * x0 + h20 * x2 * x0 + h21 * x2 * x1
                    + h30 * x3 * x0 + h31 * x3 * x1 + h32 * x3 * x2);
      }
      acc = wave_sum(acc);
      if (lane == 0) os[wave][s] = acc;
    }
  }
  __syncthreads();

  // ---- phase 5: head: out = silu(obs@W3+b3) @ W4 + b4 ----
  {
    float a00 = b3[tid],       a10 = a00;
    float a01 = b3[tid + 128], a11 = a01;
#pragma unroll
    for (int s = 0; s < NOBS; ++s) {
      float w0 = W3[s * 256 + tid];
      float w1 = W3[s * 256 + tid + 128];
      float o0 = os[0][s], o1 = os[1][s];
      a00 = fmaf(o0, w0, a00);
      a01 = fmaf(o0, w1, a01);
      a10 = fmaf(o1, w0, a10);
      a11 = fmaf(o1, w1, a11);
    }
    hs[0][tid]       = silu_f(a00);
    hs[0][tid + 128] = silu_f(a01);
    hs[1][tid]       = silu_f(a10);
    hs[1][tid + 128] = silu_f(a11);
  }
  __syncthreads();
  {
    int c = tid;                      // 0..127
    float o0 = b4[c], o1 = o0;
#pragma unroll 4
    for (int k = 0; k < 256; k += 4) {
      float w0 = W4[(k + 0) * 128 + c];
      float w1 = W4[(k + 1) * 128 + c];
      float w2 = W4[(k + 2) * 128 + c];
      float w3 = W4[(k + 3) * 128 + c];
      float4 ha = *(const float4*)&hs[0][k];
      float4 hb = *(const float4*)&hs[1][k];
      o0 = fmaf(ha.w, w3, fmaf(ha.z, w2, fmaf(ha.y, w1, fmaf(ha.x, w0, o0))));
      o1 = fmaf(hb.w, w3, fmaf(hb.z, w2, fmaf(hb.y, w1, fmaf(hb.x, w0, o1))));
    }
    out[(b0 + 0) * LATD + c] = o0;
    out[(b0 + 1) * LATD + c] = o1;
  }
}

// ---------------- launcher ----------------

extern "C" void kernel_launch(void* const* d_in, const int* in_sizes, int n_in,
                              void* d_out, int out_size, void* d_ws, size_t ws_size,
                              hipStream_t stream) {
  const float* z_t  = (const float*)d_in[0];
  const float* t    = (const float*)d_in[1];
  const float* W1   = (const float*)d_in[2];
  const float* b1   = (const float*)d_in[3];
  const float* W2   = (const float*)d_in[4];
  const float* b2   = (const float*)d_in[5];
  const float* varp = (const float*)d_in[6];
  const float* A_p  = (const float*)d_in[7];
  // d_in[8] = B_p: imaginary part of H -> contributes 0 for real psi
  const float* D_p  = (const float*)d_in[9];
  const float* W3   = (const float*)d_in[10];
  const float* b3   = (const float*)d_in[11];
  const float* W4   = (const float*)d_in[12];
  const float* b4   = (const float*)d_in[13];
  float* out = (float*)d_out;

  int B = in_sizes[1];  // t has one element per batch row

  fused_kernel<<<B / 2, 128, 0, stream>>>(z_t, t, W1, b1, W2, b2, varp,
                                          A_p, D_p, W3, b3, W4, b4, out);
}

// Round 6
// 128.200 us; speedup vs baseline: 1.0353x; 1.0353x over previous
//
#include <hip/hip_runtime.h>
#include <math.h>

#define NOBS 9
#define LATD 128

__device__ __forceinline__ float silu_f(float x) { return x / (1.f + expf(-x)); }

// ---------------- lane-exchange primitives ----------------

template<int CTRL>
__device__ __forceinline__ float dpp_perm(float x) {
  return __int_as_float(__builtin_amdgcn_update_dpp(0, __float_as_int(x), CTRL, 0xF, 0xF, true));
}
template<int PAT>
__device__ __forceinline__ float ds_swz(float x) {
  return __int_as_float(__builtin_amdgcn_ds_swizzle(__float_as_int(x), PAT));
}
__device__ __forceinline__ float x4f(float x) { return ds_swz<0x101F>(x); }   // xor4

__device__ __forceinline__ float wave_sum(float x) {
  x += dpp_perm<0xB1>(x);     // xor1
  x += dpp_perm<0x4E>(x);     // xor2
  x += x4f(x);                // xor4
  x += dpp_perm<0x128>(x);    // xor8
  x += ds_swz<0x401F>(x);     // xor16
  x += __shfl_xor(x, 32, 64); // xor32
  return x;
}

// ---------------- circuit gates (8 regs/lane, 2 waves per row) ----------------
// amp index bits: [9] = wave half w (qubit 0), [8:6] = reg bits 2..0 (qubits 1..3),
// [5:0] = lane bits (qubits 4..9 -> masks 32,16,8,4,2,1)

template<int M>
__device__ __forceinline__ void ry_reg8(float v[8], float c, float s) {
#pragma unroll
  for (int r = 0; r < 8; ++r) {
    if ((r & M) == 0) {
      float p0 = v[r], p1 = v[r | M];
      v[r]     = c * p0 - s * p1;
      v[r | M] = s * p0 + c * p1;
    }
  }
}
template<int MASK>
__device__ __forceinline__ void ry_shfl8(float v[8], float c, float s, int lane) {
  float sp = (lane & MASK) ? s : -s;
#pragma unroll
  for (int r = 0; r < 8; ++r) { float p = __shfl_xor(v[r], MASK, 64); v[r] = fmaf(c, v[r], sp * p); }
}
template<int CTRL, int MASK>
__device__ __forceinline__ void ry_dpp8(float v[8], float c, float s, int lane) {
  float sp = (lane & MASK) ? s : -s;
#pragma unroll
  for (int r = 0; r < 8; ++r) { float p = dpp_perm<CTRL>(v[r]); v[r] = fmaf(c, v[r], sp * p); }
}
__device__ __forceinline__ void ry_x4g(float v[8], float c, float s, int lane) {
  float sp = (lane & 4) ? s : -s;
#pragma unroll
  for (int r = 0; r < 8; ++r) { float p = x4f(v[r]); v[r] = fmaf(c, v[r], sp * p); }
}

// full RY layer; q0 gate exchanges across the wave pair through LDS (xbuf = row base + pb*1024)
__device__ __forceinline__ void apply_rys10(float v[8], int lane, int w,
                                            const float* __restrict__ cc,
                                            const float* __restrict__ ss,
                                            float* xbuf) {
  {  // q0: cross-wave butterfly
    float c = cc[0], s = ss[0];
    float sp = w ? s : -s;
    float* mine   = xbuf + w * 512;
    float* theirs = xbuf + (1 - w) * 512;
#pragma unroll
    for (int r = 0; r < 8; ++r) mine[r * 64 + lane] = v[r];
    __syncthreads();
#pragma unroll
    for (int r = 0; r < 8; ++r) { float p = theirs[r * 64 + lane]; v[r] = fmaf(c, v[r], sp * p); }
  }
  ry_reg8<4>(v, cc[1], ss[1]);
  ry_reg8<2>(v, cc[2], ss[2]);
  ry_reg8<1>(v, cc[3], ss[3]);
  ry_shfl8<32>(v, cc[4], ss[4], lane);
  ry_shfl8<16>(v, cc[5], ss[5], lane);
  ry_dpp8<0x128, 8>(v, cc[6], ss[6], lane);
  ry_x4g(v, cc[7], ss[7], lane);
  ry_dpp8<0x4E, 2>(v, cc[8], ss[8], lane);
  ry_dpp8<0xB1, 1>(v, cc[9], ss[9], lane);
}

__device__ __forceinline__ void cnot_ladder8(float v[8], int lane, int w) {
  // even phase: (q0,q1): ctrl = wave bit -> wave 1 flips reg bit2
#pragma unroll
  for (int r = 0; r < 4; ++r) {
    float a = v[r], b = v[r + 4];
    v[r]     = w ? b : a;
    v[r + 4] = w ? a : b;
  }
  { float t = v[2]; v[2] = v[3]; v[3] = t; }   // (q2,q3)
  { float t = v[6]; v[6] = v[7]; v[7] = t; }
  { bool c45 = (lane & 32);                    // (q4,q5): xor16
#pragma unroll
    for (int r = 0; r < 8; ++r) { float p = __shfl_xor(v[r], 16, 64); v[r] = c45 ? p : v[r]; } }
  { bool c67 = (lane & 8);                     // (q6,q7): xor4
#pragma unroll
    for (int r = 0; r < 8; ++r) { float p = x4f(v[r]); v[r] = c67 ? p : v[r]; } }
  { bool c89 = (lane & 2);                     // (q8,q9): xor1
#pragma unroll
    for (int r = 0; r < 8; ++r) { float p = dpp_perm<0xB1>(v[r]); v[r] = c89 ? p : v[r]; } }
  // odd phase: (q1,q2): reg bit2 ctrl -> flip reg bit1
  { float t = v[4]; v[4] = v[6]; v[6] = t; }
  { float t = v[5]; v[5] = v[7]; v[7] = t; }
#pragma unroll
  for (int r = 1; r < 8; r += 2) v[r] = __shfl_xor(v[r], 32, 64);  // (q3,q4): reg bit0 ctrl -> lane xor32
  { bool c56 = (lane & 16);                    // (q5,q6): xor8
#pragma unroll
    for (int r = 0; r < 8; ++r) { float p = dpp_perm<0x128>(v[r]); v[r] = c56 ? p : v[r]; } }
  { bool c78 = (lane & 4);                     // (q7,q8): xor2
#pragma unroll
    for (int r = 0; r < 8; ++r) { float p = dpp_perm<0x4E>(v[r]); v[r] = c78 ? p : v[r]; } }
}

// ---------------- fused kernel: 2 rows / 256 threads; circuit = 2 waves per row ----------------

__global__ __launch_bounds__(256) void fused_kernel(
    const float* __restrict__ z, const float* __restrict__ t,
    const float* __restrict__ W1, const float* __restrict__ b1,
    const float* __restrict__ W2, const float* __restrict__ b2,
    const float* __restrict__ varp,
    const float* __restrict__ A_p, const float* __restrict__ D_p,
    const float* __restrict__ W3, const float* __restrict__ b3,
    const float* __restrict__ W4, const float* __restrict__ b4,
    float* __restrict__ out) {
  __shared__ float xs[2][256];
  __shared__ float hs[2][256];
  __shared__ float xch[2][2][1024];     // [row][pb][w*512 + r*64 + lane]; xch[row][1] doubles as dump
  __shared__ float cs[2][40], sn[2][40];
  __shared__ float vcs[60], vsn[60];
  __shared__ float part[2][2][NOBS];
  __shared__ float os[2][NOBS];

  int tid = threadIdx.x;                // 0..255
  int b0 = blockIdx.x * 2;

  // var-layer cos/sin (redundant per block, trivial)
  if (tid < 60) {
    float s, c;
    sincosf(0.5f * varp[tid], &s, &c);
    vcs[tid] = c; vsn[tid] = s;
  }

  // ---- phase 1: x = [z, cos(t f), sin(t f)] ----
#pragma unroll
  for (int r = 0; r < 2; ++r) {
    int b = b0 + r;
    if (tid < 128) {
      xs[r][tid] = z[b * 128 + tid];
    } else {
      int i = tid - 128, j = i & 63;
      float freq = expf(-9.2103403719761836f * (float)j * (1.f / 64.f));
      float arg = t[b] * freq;
      xs[r][tid] = (i < 64) ? cosf(arg) : sinf(arg);
    }
  }
  __syncthreads();

  // ---- phase 2: h = silu(x@W1 + b1): each thread 1 col x 2 rows ----
  {
    float a0 = b1[tid], a1 = a0;
#pragma unroll 4
    for (int k = 0; k < 256; k += 4) {
      float w0 = W1[(k + 0) * 256 + tid];
      float w1 = W1[(k + 1) * 256 + tid];
      float w2 = W1[(k + 2) * 256 + tid];
      float w3 = W1[(k + 3) * 256 + tid];
      float4 x0 = *(const float4*)&xs[0][k];
      float4 x1 = *(const float4*)&xs[1][k];
      a0 = fmaf(x0.w, w3, fmaf(x0.z, w2, fmaf(x0.y, w1, fmaf(x0.x, w0, a0))));
      a1 = fmaf(x1.w, w3, fmaf(x1.z, w2, fmaf(x1.y, w1, fmaf(x1.x, w0, a1))));
    }
    hs[0][tid] = silu_f(a0);
    hs[1][tid] = silu_f(a1);
  }
  __syncthreads();

  // ---- phase 3: ang = h@W2 + b2 -> cos/sin(ang/2) (80 outputs) ----
  if (tid < 80) {
    int r = tid / 40, c = tid - r * 40;
    float acc = b2[c];
#pragma unroll 4
    for (int k = 0; k < 256; k += 4) {
      float4 h = *(const float4*)&hs[r][k];
      acc = fmaf(h.x, W2[(k + 0) * 40 + c], acc);
      acc = fmaf(h.y, W2[(k + 1) * 40 + c], acc);
      acc = fmaf(h.z, W2[(k + 2) * 40 + c], acc);
      acc = fmaf(h.w, W2[(k + 3) * 40 + c], acc);
    }
    float s, cv;
    sincosf(0.5f * acc, &s, &cv);
    cs[r][c] = cv; sn[r][c] = s;
  }
  __syncthreads();

  // ---- phase 4: circuit. wave pair (w=0,1) per row; 8 amps per lane ----
  float v[8];
  int W_id = tid >> 6;
  int row  = W_id >> 1;
  int w    = W_id & 1;
  int lane = tid & 63;
  const float* cc = cs[row];
  const float* ss = sn[row];
  float* xch_row = &xch[row][0][0];

  {
    // layer 0 on |0..0>: product state (q0 factor = wave bit)
    float base = w ? ss[0] : cc[0];
    base *= (lane & 32) ? ss[4] : cc[4];
    base *= (lane & 16) ? ss[5] : cc[5];
    base *= (lane & 8)  ? ss[6] : cc[6];
    base *= (lane & 4)  ? ss[7] : cc[7];
    base *= (lane & 2)  ? ss[8] : cc[8];
    base *= (lane & 1)  ? ss[9] : cc[9];
#pragma unroll
    for (int r = 0; r < 8; ++r) {
      float p = base;
      p *= (r & 4) ? ss[1] : cc[1];
      p *= (r & 2) ? ss[2] : cc[2];
      p *= (r & 1) ? ss[3] : cc[3];
      v[r] = p;
    }
  }
  cnot_ladder8(v, lane, w);
  int idx = 0;
#pragma unroll 1
  for (int layer = 1; layer < 4; ++layer) {
    apply_rys10(v, lane, w, cc + layer * 10, ss + layer * 10, xch_row + (idx & 1) * 1024);
    ++idx;
    if (layer < 3) cnot_ladder8(v, lane, w);
  }
#pragma unroll 1
  for (int ly = 0; ly < 6; ++ly) {
    apply_rys10(v, lane, w, vcs + ly * 10, vsn + ly * 10, xch_row + (idx & 1) * 1024);
    ++idx;
    cnot_ladder8(v, lane, w);
  }

  // dump full state of this row into xch[row][1] (amp = w*512 + r*64 + lane)
  {
    float* dmp = xch_row + 1024;
#pragma unroll
    for (int r = 0; r < 8; ++r) dmp[w * 512 + r * 64 + lane] = v[r];
  }
  __syncthreads();

  // expectation values: obs s acts on amp bits (9-s, 8-s); 256 quads, 2 per thread
  {
    const float* dmp = xch_row + 1024;
    int wl = w * 64 + lane;            // 0..127 within row
#pragma unroll 1
    for (int s = 0; s < NOBS; ++s) {
      const int r8 = 8 - s;
      const int stride = 1 << r8;
      float h10 = A_p[s*6+0], h20 = A_p[s*6+1], h21 = A_p[s*6+2];
      float h30 = A_p[s*6+3], h31 = A_p[s*6+4], h32 = A_p[s*6+5];
      float d0 = 2.f * D_p[s*4+1], d1 = 2.f * D_p[s*4+2], d2 = 2.f * D_p[s*4+3];
      float acc = 0.f;
#pragma unroll
      for (int k = 0; k < 2; ++k) {
        int p = wl + 128 * k;
        int a  = p >> r8;
        int rr = p & (stride - 1);
        int bse = (a << (r8 + 2)) + rr;
        float x0 = dmp[bse];
        float x1 = dmp[bse + stride];
        float x2 = dmp[bse + 2 * stride];
        float x3 = dmp[bse + 3 * stride];
        acc += d0 * x0 * x0 + d1 * x1 * x1 + d2 * x2 * x2
             + 2.f * (h10 * x1 * x0 + h20 * x2 * x0 + h21 * x2 * x1
                    + h30 * x3 * x0 + h31 * x3 * x1 + h32 * x3 * x2);
      }
      acc = wave_sum(acc);
      if (lane == 0) part[row][w][s] = acc;
    }
  }
  __syncthreads();
  if (tid < 2 * NOBS) {
    int r = tid / NOBS, s = tid - r * NOBS;
    os[r][s] = part[r][0][s] + part[r][1][s];
  }
  __syncthreads();

  // ---- phase 5: head: out = silu(obs@W3+b3) @ W4 + b4 ----
  {
    float a0 = b3[tid], a1 = a0;
#pragma unroll
    for (int s = 0; s < NOBS; ++s) {
      float wv = W3[s * 256 + tid];
      a0 = fmaf(os[0][s], wv, a0);
      a1 = fmaf(os[1][s], wv, a1);
    }
    hs[0][tid] = silu_f(a0);
    hs[1][tid] = silu_f(a1);
  }
  __syncthreads();
  {
    int c = tid & 127, rg = tid >> 7;
    const float* h = hs[rg];
    float o = b4[c];
#pragma unroll 4
    for (int k = 0; k < 256; k += 4) {
      float w0 = W4[(k + 0) * 128 + c];
      float w1 = W4[(k + 1) * 128 + c];
      float w2 = W4[(k + 2) * 128 + c];
      float w3 = W4[(k + 3) * 128 + c];
      float4 ha = *(const float4*)&h[k];
      o = fmaf(ha.w, w3, fmaf(ha.z, w2, fmaf(ha.y, w1, fmaf(ha.x, w0, o))));
    }
    out[(b0 + rg) * LATD + c] = o;
  }
}

// ---------------- launcher ----------------

extern "C" void kernel_launch(void* const* d_in, const int* in_sizes, int n_in,
                              void* d_out, int out_size, void* d_ws, size_t ws_size,
                              hipStream_t stream) {
  const float* z_t  = (const float*)d_in[0];
  const float* t    = (const float*)d_in[1];
  const float* W1   = (const float*)d_in[2];
  const float* b1   = (const float*)d_in[3];
  const float* W2   = (const float*)d_in[4];
  const float* b2   = (const float*)d_in[5];
  const float* varp = (const float*)d_in[6];
  const float* A_p  = (const float*)d_in[7];
  // d_in[8] = B_p: imaginary part of H -> contributes 0 for real psi
  const float* D_p  = (const float*)d_in[9];
  const float* W3   = (const float*)d_in[10];
  const float* b3   = (const float*)d_in[11];
  const float* W4   = (const float*)d_in[12];
  const float* b4   = (const float*)d_in[13];
  float* out = (float*)d_out;

  int B = in_sizes[1];  // t has one element per batch row

  fused_kernel<<<B / 2, 256, 0, stream>>>(z_t, t, W1, b1, W2, b2, varp,
                                          A_p, D_p, W3, b3, W4, b4, out);
}